// Round 1
// baseline (177.700 us; speedup 1.0000x reference)
//
#include <hip/hip_runtime.h>

#define DIM 32

__global__ void gc_scatter(const int* __restrict__ rows,
                           const int* __restrict__ cols,
                           const float* __restrict__ vals,
                           const float* __restrict__ feat,
                           float* __restrict__ out,
                           int n_edges) {
    long long gid = (long long)blockIdx.x * blockDim.x + threadIdx.x;
    int e = (int)(gid >> 5);       // edge index: 32 consecutive lanes share one edge
    int d = (int)(gid & 31);       // feature dim
    if (e >= n_edges) return;
    int r = rows[e];               // broadcast within the 32-lane group (L1 hit)
    int c = cols[e];
    float v = vals[e];
    float f = feat[(long long)c * DIM + d];   // 128B coalesced gather per edge
    atomicAdd(&out[(long long)r * DIM + d], v * f);
}

extern "C" void kernel_launch(void* const* d_in, const int* in_sizes, int n_in,
                              void* d_out, int out_size, void* d_ws, size_t ws_size,
                              hipStream_t stream) {
    const int*   rows = (const int*)d_in[0];
    const int*   cols = (const int*)d_in[1];
    const float* vals = (const float*)d_in[2];
    const float* feat = (const float*)d_in[3];
    float*       out  = (float*)d_out;

    const int n_edges = in_sizes[0];

    // d_out is poisoned with 0xAA before timing; we must zero it ourselves.
    hipMemsetAsync(out, 0, (size_t)out_size * sizeof(float), stream);

    long long total  = (long long)n_edges * DIM;   // one thread per (edge, dim)
    const int block  = 256;
    unsigned  nblock = (unsigned)((total + block - 1) / block);
    gc_scatter<<<nblock, block, 0, stream>>>(rows, cols, vals, feat, out, n_edges);
}